// Round 16
// baseline (190.631 us; speedup 1.0000x reference)
//
#include <hip/hip_runtime.h>
#include <stdint.h>

#define B_ 64
#define F2_ 256
#define J_ 25
#define FILT_ 64
#define C1_ 1600   // J*FILT
#define O1_ 128
#define NN_ 409600 // B*F*J
#define MM_ 16384  // B*F
#define EPSV 1e-5f

typedef short short8 __attribute__((ext_vector_type(8)));
typedef float f32x4 __attribute__((ext_vector_type(4)));

// ---- workspace layout (bytes) ----
// y2t: bf16 [64][258][1600]  (rows 0 and 257 per batch are zero pads)
static const size_t WS_Y2T  = 0;                       // 52,838,400
static const size_t WS_XA   = 52838400;                // f32 [NN][3] 4,915,200
static const size_t WS_WT1  = 57753600;                // bf16 [3][128][1600] 1,228,800
static const size_t WS_WT2  = 58982400;                // bf16 [64][128] 16,384
static const size_t WS_WT2G = 58998784;                // bf16 [64][64] 8,192
static const size_t WS_Y3   = 59006976;                // f32 [64][256][128] 8,388,608
static const size_t WS_Y4   = 67395584;                // f32 [64][256][64] 4,194,304
static const size_t WS_ST   = 71589888;                // f32 stats block
// stats block float offsets
#define ST_S9    0
#define ST_SUM2  16
#define ST_SQ2   80
#define ST_SUM3  144
#define ST_SQ3   272
#define ST_SUM4  400
#define ST_SQ4   464
#define ST_COUNT 528

__device__ __forceinline__ float bf2f(unsigned int u){
  return __uint_as_float(u << 16);
}
__device__ __forceinline__ unsigned short f2bf(float f){
  unsigned int u = __float_as_uint(f);
  u += 0x7fffu + ((u >> 16) & 1u);   // RNE
  return (unsigned short)(u >> 16);
}
__device__ __forceinline__ float lrelu(float x){ return fmaxf(x, 0.2f * x); }
__device__ __forceinline__ float wsum(float v){
  #pragma unroll
  for (int off = 32; off > 0; off >>= 1) v += __shfl_down(v, off, 64);
  return v;
}

typedef __attribute__((address_space(3))) unsigned int lds_uint_t;
typedef __attribute__((address_space(1))) const unsigned int glob_uint_t;
__device__ __forceinline__ void gl16(const void* g, void* l){
  __builtin_amdgcn_global_load_lds((glob_uint_t*)g, (lds_uint_t*)l, 16, 0, 0);
}

// ---- weight transforms + y2t pad-row zeroing (fused) ----
__global__ __launch_bounds__(256) void k_wt(const float* __restrict__ cw1,
                                            const float* __restrict__ W2,
                                            const float* __restrict__ cw2,
                                            unsigned short* __restrict__ wt1,
                                            unsigned short* __restrict__ wt2,
                                            unsigned short* __restrict__ wt2g,
                                            unsigned short* __restrict__ y2t){
  int blk = blockIdx.x;
  if (blk < 384){
    int k = blk >> 7, o = blk & 127;
    for (int c = threadIdx.x; c < 1600; c += 256)
      wt1[(size_t)(k * 128 + o) * 1600 + c] = f2bf(cw1[(size_t)(o * 1600 + c) * 3 + k]);
  } else if (blk < 416){
    int idx = ((blk - 384) << 8) + threadIdx.x;   // 8192
    wt2[idx] = f2bf(cw2[idx]);
  } else if (blk < 432){
    int idx = ((blk - 416) << 8) + threadIdx.x;   // 4096
    int f = idx >> 6, cc = idx & 63;
    wt2g[idx] = f2bf(W2[cc * 64 + f]);
  } else {
    int b = blk - 432, tid = threadIdx.x;
    if (tid < 200){
      uint4 z = make_uint4(0,0,0,0);
      ((uint4*)(y2t + (size_t)b * 412800))[tid] = z;
      ((uint4*)(y2t + (size_t)b * 412800 + 257 * 1600))[tid] = z;
    }
  }
}

// ---- GCN1 aggregate + 9-scalar moments ----
__global__ __launch_bounds__(256) void k_gcn1(const float* __restrict__ x,
                                              float* __restrict__ xa,
                                              float* __restrict__ S9){
  int n = blockIdx.x * 256 + threadIdx.x;
  int j = n % J_;
  float dj  = (j == 0 || j == J_-1) ? 2.f : 3.f;
  float rdj = rsqrtf(dj);
  const float* xp = x + (size_t)n * 3;
  float wg = 1.f / dj;
  float a0 = xp[0]*wg, a1 = xp[1]*wg, a2 = xp[2]*wg;
  if (j > 0){
    float dm = (j == 1) ? 2.f : 3.f;  float w = rdj * rsqrtf(dm);
    a0 += xp[-3]*w; a1 += xp[-2]*w; a2 += xp[-1]*w;
  }
  if (j < J_-1){
    float dp = (j == J_-2) ? 2.f : 3.f;  float w = rdj * rsqrtf(dp);
    a0 += xp[3]*w; a1 += xp[4]*w; a2 += xp[5]*w;
  }
  float* xo = xa + (size_t)n * 3;
  xo[0] = a0; xo[1] = a1; xo[2] = a2;
  float p[9] = {a0, a1, a2, a0*a0, a0*a1, a0*a2, a1*a1, a1*a2, a2*a2};
  __shared__ float tmp[9][4];
  int wv = threadIdx.x >> 6, ln = threadIdx.x & 63;
  #pragma unroll
  for (int k = 0; k < 9; k++){ float s = wsum(p[k]); if (ln == 0) tmp[k][wv] = s; }
  __syncthreads();
  if (threadIdx.x < 9){
    int k = threadIdx.x;
    atomicAdd(S9 + k, tmp[k][0] + tmp[k][1] + tmp[k][2] + tmp[k][3]);
  }
}

// ---- GCN2 via MFMA: 4-way STATIC j-split (J0=6*jh, all %3==0 -> same ring),
//      full bf16 xas (no dynamic indexing), grid 1024 -> 4 blocks/CU;
//      fused BN1-param + BN2 stats; scattered stores ----
#define H1SLICE(ph, js) do { \
  int js_ = (js); \
  _Pragma("unroll") \
  for (int i_ = 0; i_ < 16; i_++){ \
    const unsigned short* xp_ = xas + ((wl0 + i_) * 25 + js_) * 3; \
    float x0_ = bf2f(xp_[0]), x1_ = bf2f(xp_[1]), x2_ = bf2f(xp_[2]); \
    h[ph][i_] = lrelu(fmaf(sS, fmaf(x0_, w0c, fmaf(x1_, w1c, x2_*w2c)), tT)); \
  } } while(0)

#define AGGW(pm, pc, pp) do { \
  _Pragma("unroll") \
  for (int i_ = 0; i_ < 16; i_++){ \
    float a_ = wgm*h[pm][i_] + wgs*h[pc][i_] + wgp*h[pp][i_]; \
    int row_ = wl0 + i_; \
    *(unsigned short*)(As + row_*128 + ((((lane>>3)) ^ (row_&7))<<4) + ((lane&7)<<1)) = f2bf(a_); \
  } } while(0)

__global__ __launch_bounds__(256) void k_gcn2m(const float* __restrict__ xa,
                                               const float* __restrict__ W1,
                                               const float* __restrict__ S9,
                                               const float* __restrict__ b1,
                                               const float* __restrict__ g1,
                                               const float* __restrict__ be1,
                                               const float* __restrict__ b2,
                                               const unsigned short* __restrict__ wt2g,
                                               unsigned short* __restrict__ y2t,
                                               float* __restrict__ sum2,
                                               float* __restrict__ sq2){
  __shared__ unsigned short xas[4800]; // [64 l][25 j][3 d] bf16 (9.6KB)
  __shared__ float prm[384];           // W1(192) s1(64) t1(64) b2(64)
  __shared__ char As[8192];            // agg tile [64 l][64 cc] bf16, swizzled
  __shared__ char Bs[8192];            // wt2g tile [64 f][64 cc] bf16, swizzled
  int blk = blockIdx.x;                // 1024 = ((b*4)+lq)*4 + jh
  int jh = blk & 3;
  int lq = (blk >> 2) & 3;
  int b  = blk >> 4;
  int l0 = lq << 6;
  int tid = threadIdx.x;
  int w = tid >> 6, lane = tid & 63;

  const float* xsrc = xa + (size_t)(b * 256 + l0) * 75;
  #pragma unroll
  for (int i = 0; i < 5; i++){
    int idx = tid + (i << 8);
    if (idx < 1200){
      float4 v = ((const float4*)xsrc)[idx];
      uint2 u;
      u.x = (unsigned)f2bf(v.x) | ((unsigned)f2bf(v.y) << 16);
      u.y = (unsigned)f2bf(v.z) | ((unsigned)f2bf(v.w) << 16);
      ((uint2*)xas)[idx] = u;
    }
  }
  if (tid < 192) prm[tid] = W1[tid];
  else if (tid < 256) prm[tid + 128] = b2[tid - 192];   // prm[320..383] = b2
  if (tid < 64){
    float inv = 1.f / (float)NN_;
    float m0 = S9[0]*inv, m1 = S9[1]*inv, m2 = S9[2]*inv;
    float C00 = S9[3]*inv - m0*m0, C01 = S9[4]*inv - m0*m1, C02 = S9[5]*inv - m0*m2;
    float C11 = S9[6]*inv - m1*m1, C12 = S9[7]*inv - m1*m2, C22 = S9[8]*inv - m2*m2;
    float w0 = W1[tid], w1 = W1[64+tid], w2 = W1[128+tid];
    float mean = m0*w0 + m1*w1 + m2*w2 + b1[tid];
    float var  = w0*w0*C00 + w1*w1*C11 + w2*w2*C22
               + 2.f*(w0*w1*C01 + w0*w2*C02 + w1*w2*C12);
    float s = g1[tid] * rsqrtf(var + EPSV);
    prm[192 + tid] = s;
    prm[256 + tid] = be1[tid] - s*mean + s*b1[tid];
  }
  #pragma unroll
  for (int i = 0; i < 2; i++){
    int r = (w << 4) + (i << 3) + (lane >> 3);
    int cblk = lane & 7;
    gl16(wt2g + (size_t)r * 64 + (((cblk ^ (r & 7))) << 3),
         Bs + (w << 11) + (i << 10));
  }
  __syncthreads();   // prologue barrier

  float w0c = prm[lane], w1c = prm[64 + lane], w2c = prm[128 + lane];
  float sS = prm[192 + lane], tT = prm[256 + lane];
  int wm = w >> 1, wn = w & 1;
  int m0 = (wm << 5) + (lane & 15);
  int n0 = (wn << 5) + (lane & 15);
  int kg = lane >> 4;
  float bias0 = prm[320 + n0], bias1 = prm[320 + n0 + 16];
  int wl0 = w << 4;

  float h[3][16];
  int J0 = jh * 6;                 // 0, 6, 12, 18 — all %3==0, static ring phases
  int NJ = (jh == 3) ? 7 : 6;
  #pragma unroll
  for (int i = 0; i < 16; i++) h[2][i] = 0.f;
  H1SLICE(0, J0);
  if (J0 > 0) H1SLICE(2, J0 - 1);

  float ss0 = 0.f, ss1 = 0.f, qq0 = 0.f, qq1 = 0.f;

  #pragma unroll
  for (int jj = 0; jj < 7; jj++){
    if (jj >= NJ) break;
    int j = J0 + jj;
    if (j + 1 <= 24){
      switch ((jj + 1) % 3){
        case 0: H1SLICE(0, j + 1); break;
        case 1: H1SLICE(1, j + 1); break;
        case 2: H1SLICE(2, j + 1); break;
      }
    }
    float dj  = (j == 0 || j == 24) ? 2.f : 3.f;
    float rdj = rsqrtf(dj);
    float wgs = 1.f / dj;
    float wgm = (j > 0)  ? rdj * rsqrtf((j == 1)  ? 2.f : 3.f) : 0.f;
    float wgp = (j < 24) ? rdj * rsqrtf((j == 23) ? 2.f : 3.f) : 0.f;
    switch (jj % 3){
      case 0: AGGW(2, 0, 1); break;
      case 1: AGGW(0, 1, 2); break;
      case 2: AGGW(1, 2, 0); break;
    }
    __syncthreads();   // As visible
    f32x4 acc[2][2] = {};
    #pragma unroll
    for (int ks = 0; ks < 2; ks++){
      int kb = kg + (ks << 2);
      short8 a0 = *(const short8*)(As + (m0 << 7)        + ((kb ^ (m0 & 7)) << 4));
      short8 a1 = *(const short8*)(As + ((m0 + 16) << 7) + ((kb ^ (m0 & 7)) << 4));
      short8 b0 = *(const short8*)(Bs + (n0 << 7)        + ((kb ^ (n0 & 7)) << 4));
      short8 b1 = *(const short8*)(Bs + ((n0 + 16) << 7) + ((kb ^ (n0 & 7)) << 4));
      acc[0][0] = __builtin_amdgcn_mfma_f32_16x16x32_bf16(a0, b0, acc[0][0], 0, 0, 0);
      acc[0][1] = __builtin_amdgcn_mfma_f32_16x16x32_bf16(a0, b1, acc[0][1], 0, 0, 0);
      acc[1][0] = __builtin_amdgcn_mfma_f32_16x16x32_bf16(a1, b0, acc[1][0], 0, 0, 0);
      acc[1][1] = __builtin_amdgcn_mfma_f32_16x16x32_bf16(a1, b1, acc[1][1], 0, 0, 0);
    }
    __syncthreads();   // As reads done -> reusable next j
    // epilogue: bias + stats partials + scattered bf16 stores (R4-proven)
    int rowb = (wm << 5) + ((lane >> 4) << 2);
    #pragma unroll
    for (int mi = 0; mi < 2; mi++){
      #pragma unroll
      for (int ni = 0; ni < 2; ni++){
        float bias = ni ? bias1 : bias0;
        int f = n0 + (ni << 4);
        #pragma unroll
        for (int r = 0; r < 4; r++){
          float v = acc[mi][ni][r] + bias;
          if (ni){ ss1 += v; qq1 += v * v; } else { ss0 += v; qq0 += v * v; }
          int rl = rowb + (mi << 4) + r;
          y2t[(size_t)(b * 258 + l0 + rl + 1) * 1600 + j * 64 + f] = f2bf(v);
        }
      }
    }
  }
  ss0 += __shfl_xor(ss0, 16, 64); ss0 += __shfl_xor(ss0, 32, 64);
  ss1 += __shfl_xor(ss1, 16, 64); ss1 += __shfl_xor(ss1, 32, 64);
  qq0 += __shfl_xor(qq0, 16, 64); qq0 += __shfl_xor(qq0, 32, 64);
  qq1 += __shfl_xor(qq1, 16, 64); qq1 += __shfl_xor(qq1, 32, 64);
  if ((lane >> 4) == 0){
    atomicAdd(sum2 + n0, ss0);      atomicAdd(sq2 + n0, qq0);
    atomicAdd(sum2 + n0 + 16, ss1); atomicAdd(sq2 + n0 + 16, qq1);
  }
}

// ---- BN2+lrelu in place on y2t (pads stay zero) + fused BN2-param computation ----
__global__ __launch_bounds__(256) void k_bnapp2(unsigned short* __restrict__ y2t,
                                                const float* __restrict__ sum2,
                                                const float* __restrict__ sq2,
                                                const float* __restrict__ g2,
                                                const float* __restrict__ be2){
  __shared__ float scL[64], shL[64];
  int tid = threadIdx.x;
  if (tid < 64){
    float inv = 1.f / (float)NN_;
    float mean = sum2[tid] * inv;
    float var  = sq2[tid] * inv - mean * mean;
    float s = g2[tid] * rsqrtf(var + EPSV);
    scL[tid] = s; shL[tid] = be2[tid] - s * mean;
  }
  __syncthreads();
  for (unsigned idx = blockIdx.x * 256 + tid; idx < 3276800u; idx += 524288u){
    unsigned b = idx / 51200u;
    unsigned rem = idx - b * 51200u;
    unsigned l = rem / 200u;
    unsigned cg = rem - l * 200u;
    uint4* p = (uint4*)y2t + ((size_t)b * 258 + l + 1) * 200 + cg;
    unsigned f0 = (cg << 3) & 63u;
    float scs[8], shs[8];
    #pragma unroll
    for (int i = 0; i < 8; i++){ scs[i] = scL[f0 + i]; shs[i] = shL[f0 + i]; }
    uint4 v = *p;
    unsigned vv[4] = {v.x,v.y,v.z,v.w};
    unsigned r[4];
    #pragma unroll
    for (int i = 0; i < 4; i++){
      float lo = bf2f(vv[i] & 0xffffu);
      float hi = bf2f(vv[i] >> 16);
      lo = lrelu(fmaf(scs[2*i],   lo, shs[2*i]));
      hi = lrelu(fmaf(scs[2*i+1], hi, shs[2*i+1]));
      r[i] = (unsigned)f2bf(lo) | (((unsigned)f2bf(hi)) << 16);
    }
    *p = make_uint4(r[0],r[1],r[2],r[3]);
  }
}

// ---- conv1 as MFMA GEMM + fused stats3; t-order (cc outer, k inner) for L2 tap reuse ----
#define NT_ 75
__global__ __launch_bounds__(256) void k_conv1(const unsigned short* __restrict__ y2t,
                                               const unsigned short* __restrict__ wt1,
                                               const float* __restrict__ cb1,
                                               float* __restrict__ y3,
                                               float* __restrict__ sum3,
                                               float* __restrict__ sq3){
  __shared__ char smem[32768];
  // XCD-aware swizzle: og/lq/b siblings land on the same XCD for L2 dedup
  int bid = blockIdx.x;          // 512
  int blk = ((bid & 7) << 6) | (bid >> 3);
  int b  = blk >> 3;
  int lq = (blk >> 1) & 3;
  int og = blk & 1;
  int l0 = lq << 6;
  int tid = threadIdx.x;
  int w = tid >> 6, lane = tid & 63;
  int wm = w >> 1, wn = w & 1;
  const unsigned short* y2b = y2t + (size_t)b * 412800;
  const unsigned short* wtb = wt1 + (size_t)og * 64 * 1600;

  int rs = (w << 4) + (lane >> 3);
  int cblk = lane & 7;
  int m0 = (wm << 5) + (lane & 15);
  int n0 = (wn << 5) + (lane & 15);
  int kg = lane >> 4;

  f32x4 acc[2][2] = {};

  auto stage = [&](int t, int buf){
    int cc6 = (t * 0x5556) >> 16;          // t / 3 for t < 75
    int k   = t - cc6 * 3;
    int cc  = cc6 << 6;
    const unsigned short* wk = wtb + (size_t)k * 204800;
    #pragma unroll
    for (int i = 0; i < 2; i++){
      int r = rs + (i << 3);
      int sw = (cblk ^ (r & 7)) << 3;
      gl16(y2b + (size_t)(l0 + r + k) * 1600 + cc + sw,
           smem + buf * 16384 + (w << 11) + (i << 10));
      gl16(wk + (size_t)r * 1600 + cc + sw,
           smem + buf * 16384 + 8192 + (w << 11) + (i << 10));
    }
  };

  stage(0, 0);
  __syncthreads();
  #pragma unroll 2
  for (int t = 0; t < NT_; ++t){
    int buf = t & 1;
    if (t + 1 < NT_) stage(t + 1, buf ^ 1);
    const char* Ab = smem + buf * 16384;
    const char* Bb = Ab + 8192;
    #pragma unroll
    for (int ks = 0; ks < 2; ks++){
      int kb = kg + (ks << 2);
      short8 a0 = *(const short8*)(Ab + (m0 << 7)        + ((kb ^ (m0 & 7)) << 4));
      short8 a1 = *(const short8*)(Ab + ((m0 + 16) << 7) + ((kb ^ (m0 & 7)) << 4));
      short8 b0 = *(const short8*)(Bb + (n0 << 7)        + ((kb ^ (n0 & 7)) << 4));
      short8 b1 = *(const short8*)(Bb + ((n0 + 16) << 7) + ((kb ^ (n0 & 7)) << 4));
      acc[0][0] = __builtin_amdgcn_mfma_f32_16x16x32_bf16(a0, b0, acc[0][0], 0, 0, 0);
      acc[0][1] = __builtin_amdgcn_mfma_f32_16x16x32_bf16(a0, b1, acc[0][1], 0, 0, 0);
      acc[1][0] = __builtin_amdgcn_mfma_f32_16x16x32_bf16(a1, b0, acc[1][0], 0, 0, 0);
      acc[1][1] = __builtin_amdgcn_mfma_f32_16x16x32_bf16(a1, b1, acc[1][1], 0, 0, 0);
    }
    __syncthreads();
  }

  int colb = (og << 6) + n0;
  int rowb = l0 + (wm << 5) + ((lane >> 4) << 2);
  float ss0 = 0.f, ss1 = 0.f, qq0 = 0.f, qq1 = 0.f;
  #pragma unroll
  for (int mi = 0; mi < 2; mi++){
    #pragma unroll
    for (int ni = 0; ni < 2; ni++){
      int col = colb + (ni << 4);
      float bias = cb1[col];
      #pragma unroll
      for (int r = 0; r < 4; r++){
        float v = acc[mi][ni][r] + bias;
        if (ni){ ss1 += v; qq1 += v * v; } else { ss0 += v; qq0 += v * v; }
        y3[(size_t)((b << 8) + rowb + (mi << 4) + r) * 128 + col] = v;
      }
    }
  }
  ss0 += __shfl_xor(ss0, 16, 64); ss0 += __shfl_xor(ss0, 32, 64);
  ss1 += __shfl_xor(ss1, 16, 64); ss1 += __shfl_xor(ss1, 32, 64);
  qq0 += __shfl_xor(qq0, 16, 64); qq0 += __shfl_xor(qq0, 32, 64);
  qq1 += __shfl_xor(qq1, 16, 64); qq1 += __shfl_xor(qq1, 32, 64);
  if ((lane >> 4) == 0){
    atomicAdd(sum3 + colb, ss0);      atomicAdd(sq3 + colb, qq0);
    atomicAdd(sum3 + colb + 16, ss1); atomicAdd(sq3 + colb + 16, qq1);
  }
}

// ---- conv2 MFMA + fused BN3-param compute + BN3/lrelu on A-staging + fused stats4 ----
__global__ __launch_bounds__(256) void k_conv2(const float* __restrict__ y3,
                                               const float* __restrict__ sum3,
                                               const float* __restrict__ sq3,
                                               const float* __restrict__ cg1,
                                               const float* __restrict__ cbe1,
                                               const unsigned short* __restrict__ wt2,
                                               const float* __restrict__ cb2,
                                               float* __restrict__ y4,
                                               float* __restrict__ sum4,
                                               float* __restrict__ sq4){
  __shared__ char smem[32768];
  __shared__ float sc3s[128], sh3s[128];
  int blk = blockIdx.x;          // 256 = 64b * 4lq
  int b = blk >> 2, lq = blk & 3;
  int l0 = lq << 6;
  int tid = threadIdx.x;
  int w = tid >> 6, lane = tid & 63;
  int wm = w >> 1, wn = w & 1;
  #pragma unroll
  for (int i = 0; i < 4; i++){
    int r = (w << 4) + (i << 2) + (lane >> 4);
    int sw = (((lane & 15) ^ (r & 7)) << 3);
    gl16(wt2 + (size_t)r * 128 + sw, smem + 16384 + (w << 12) + (i << 10));
  }
  if (tid < 128){
    float inv = 1.f / (float)MM_;
    float mean = sum3[tid] * inv;
    float var  = sq3[tid] * inv - mean * mean;
    float s = cg1[tid] * rsqrtf(var + EPSV);
    sc3s[tid] = s; sh3s[tid] = cbe1[tid] - s * mean;
  }
  __syncthreads();
  #pragma unroll
  for (int i = 0; i < 4; i++){
    int idx = tid + (i << 8);
    int r = idx >> 4, s = idx & 15;
    const float* src = y3 + (size_t)((b << 8) + l0 + r) * 128 + (s << 3);
    float4 v0 = *(const float4*)(src);
    float4 v1 = *(const float4*)(src + 4);
    float4 c0 = *(const float4*)(sc3s + (s << 3));
    float4 c1 = *(const float4*)(sc3s + (s << 3) + 4);
    float4 h0 = *(const float4*)(sh3s + (s << 3));
    float4 h1 = *(const float4*)(sh3s + (s << 3) + 4);
    uint4 u;
    u.x = (unsigned)f2bf(lrelu(fmaf(c0.x, v0.x, h0.x))) |
          ((unsigned)f2bf(lrelu(fmaf(c0.y, v0.y, h0.y))) << 16);
    u.y = (unsigned)f2bf(lrelu(fmaf(c0.z, v0.z, h0.z))) |
          ((unsigned)f2bf(lrelu(fmaf(c0.w, v0.w, h0.w))) << 16);
    u.z = (unsigned)f2bf(lrelu(fmaf(c1.x, v1.x, h1.x))) |
          ((unsigned)f2bf(lrelu(fmaf(c1.y, v1.y, h1.y))) << 16);
    u.w = (unsigned)f2bf(lrelu(fmaf(c1.z, v1.z, h1.z))) |
          ((unsigned)f2bf(lrelu(fmaf(c1.w, v1.w, h1.w))) << 16);
    *(uint4*)(smem + r * 256 + ((s ^ (r & 7)) << 4)) = u;
  }
  __syncthreads();
  f32x4 acc[2][2] = {};
  int m0 = (wm << 5) + (lane & 15);
  int n0 = (wn << 5) + (lane & 15);
  int kg = lane >> 4;
  const char* Ab = smem;
  const char* Bb = smem + 16384;
  #pragma unroll
  for (int ks = 0; ks < 4; ks++){
    int kb = kg + (ks << 2);
    short8 a0 = *(const short8*)(Ab + (m0 << 8)        + ((kb ^ (m0 & 7)) << 4));
    short8 a1 = *(const short8*)(Ab + ((m0 + 16) << 8) + ((kb ^ (m0 & 7)) << 4));
    short8 b0 = *(const short8*)(Bb + (n0 << 8)        + ((kb ^ (n0 & 7)) << 4));
    short8 b1 = *(const short8*)(Bb + ((n0 + 16) << 8) + ((kb ^ (n0 & 7)) << 4));
    acc[0][0] = __builtin_amdgcn_mfma_f32_16x16x32_bf16(a0, b0, acc[0][0], 0, 0, 0);
    acc[0][1] = __builtin_amdgcn_mfma_f32_16x16x32_bf16(a0, b1, acc[0][1], 0, 0, 0);
    acc[1][0] = __builtin_amdgcn_mfma_f32_16x16x32_bf16(a1, b0, acc[1][0], 0, 0, 0);
    acc[1][1] = __builtin_amdgcn_mfma_f32_16x16x32_bf16(a1, b1, acc[1][1], 0, 0, 0);
  }
  int rowb = l0 + (wm << 5) + ((lane >> 4) << 2);
  float ss0 = 0.f, ss1 = 0.f, qq0 = 0.f, qq1 = 0.f;
  #pragma unroll
  for (int mi = 0; mi < 2; mi++){
    #pragma unroll
    for (int ni = 0; ni < 2; ni++){
      int f = n0 + (ni << 4);
      float bias = cb2[f];
      #pragma unroll
      for (int r = 0; r < 4; r++){
        float v = acc[mi][ni][r] + bias;
        if (ni){ ss1 += v; qq1 += v * v; } else { ss0 += v; qq0 += v * v; }
        y4[(size_t)((b << 8) + rowb + (mi << 4) + r) * 64 + f] = v;
      }
    }
  }
  ss0 += __shfl_xor(ss0, 16, 64); ss0 += __shfl_xor(ss0, 32, 64);
  ss1 += __shfl_xor(ss1, 16, 64); ss1 += __shfl_xor(ss1, 32, 64);
  qq0 += __shfl_xor(qq0, 16, 64); qq0 += __shfl_xor(qq0, 32, 64);
  qq1 += __shfl_xor(qq1, 16, 64); qq1 += __shfl_xor(qq1, 32, 64);
  if ((lane >> 4) == 0){
    atomicAdd(sum4 + n0, ss0);      atomicAdd(sq4 + n0, qq0);
    atomicAdd(sum4 + n0 + 16, ss1); atomicAdd(sq4 + n0 + 16, qq1);
  }
}

// ---- final: out = lrelu(bn4(y4)) + fused BN4-param compute ----
__global__ __launch_bounds__(256) void k_final(const float* __restrict__ y4,
                                               const float* __restrict__ sum4,
                                               const float* __restrict__ sq4,
                                               const float* __restrict__ cg2,
                                               const float* __restrict__ cbe2,
                                               float* __restrict__ out){
  __shared__ float sc4s[64], sh4s[64];
  int tid = threadIdx.x;
  if (tid < 64){
    float inv = 1.f / (float)MM_;
    float mean = sum4[tid] * inv;
    float var  = sq4[tid] * inv - mean * mean;
    float s = cg2[tid] * rsqrtf(var + EPSV);
    sc4s[tid] = s; sh4s[tid] = cbe2[tid] - s * mean;
  }
  __syncthreads();
  unsigned q = blockIdx.x * 256 + tid;
  unsigned f0 = (q & 15) << 2;
  float4 v = ((const float4*)y4)[q];
  float4 sc = *(const float4*)(sc4s + f0);
  float4 sh = *(const float4*)(sh4s + f0);
  v.x = lrelu(fmaf(sc.x, v.x, sh.x));
  v.y = lrelu(fmaf(sc.y, v.y, sh.y));
  v.z = lrelu(fmaf(sc.z, v.z, sh.z));
  v.w = lrelu(fmaf(sc.w, v.w, sh.w));
  ((float4*)out)[q] = v;
}

extern "C" void kernel_launch(void* const* d_in, const int* in_sizes, int n_in,
                              void* d_out, int out_size, void* d_ws, size_t ws_size,
                              hipStream_t stream){
  const float* x    = (const float*)d_in[0];
  const float* W1   = (const float*)d_in[4];
  const float* b1   = (const float*)d_in[5];
  const float* g1   = (const float*)d_in[6];
  const float* be1  = (const float*)d_in[7];
  const float* W2   = (const float*)d_in[8];
  const float* b2   = (const float*)d_in[9];
  const float* g2   = (const float*)d_in[10];
  const float* be2  = (const float*)d_in[11];
  const float* cw1  = (const float*)d_in[12];
  const float* cb1  = (const float*)d_in[13];
  const float* cg1  = (const float*)d_in[14];
  const float* cbe1 = (const float*)d_in[15];
  const float* cw2  = (const float*)d_in[16];
  const float* cb2  = (const float*)d_in[17];
  const float* cg2  = (const float*)d_in[18];
  const float* cbe2 = (const float*)d_in[19];

  char* ws = (char*)d_ws;
  unsigned short* y2t  = (unsigned short*)(ws + WS_Y2T);
  float* xa            = (float*)(ws + WS_XA);
  unsigned short* wt1  = (unsigned short*)(ws + WS_WT1);
  unsigned short* wt2  = (unsigned short*)(ws + WS_WT2);
  unsigned short* wt2g = (unsigned short*)(ws + WS_WT2G);
  float* y3            = (float*)(ws + WS_Y3);
  float* y4            = (float*)(ws + WS_Y4);
  float* st            = (float*)(ws + WS_ST);

  if (ws_size < WS_ST + ST_COUNT * 4) return;

  hipMemsetAsync(st, 0, ST_COUNT * 4, stream);
  k_wt    <<<496, 256, 0, stream>>>(cw1, W2, cw2, wt1, wt2, wt2g, y2t);
  k_gcn1  <<<1600, 256, 0, stream>>>(x, xa, st + ST_S9);
  k_gcn2m <<<1024, 256, 0, stream>>>(xa, W1, st + ST_S9, b1, g1, be1, b2, wt2g,
                                     y2t, st + ST_SUM2, st + ST_SQ2);
  k_bnapp2<<<2048, 256, 0, stream>>>(y2t, st + ST_SUM2, st + ST_SQ2, g2, be2);
  k_conv1 <<<512, 256, 0, stream>>>(y2t, wt1, cb1, y3, st + ST_SUM3, st + ST_SQ3);
  k_conv2 <<<256, 256, 0, stream>>>(y3, st + ST_SUM3, st + ST_SQ3, cg1, cbe1,
                                    wt2, cb2, y4, st + ST_SUM4, st + ST_SQ4);
  k_final <<<1024, 256, 0, stream>>>(y4, st + ST_SUM4, st + ST_SQ4, cg2, cbe2,
                                     (float*)d_out);
}

// Round 17
// 166.731 us; speedup vs baseline: 1.1433x; 1.1433x over previous
//
#include <hip/hip_runtime.h>
#include <stdint.h>

#define B_ 64
#define F2_ 256
#define J_ 25
#define FILT_ 64
#define C1_ 1600   // J*FILT
#define O1_ 128
#define NN_ 409600 // B*F*J
#define MM_ 16384  // B*F
#define EPSV 1e-5f

typedef short short8 __attribute__((ext_vector_type(8)));
typedef float f32x4 __attribute__((ext_vector_type(4)));

// ---- workspace layout (bytes) ----
// y2t: bf16 [64][258][1600]  (rows 0 and 257 per batch are zero pads)
static const size_t WS_Y2T  = 0;                       // 52,838,400
static const size_t WS_XA   = 52838400;                // f32 [NN][3] 4,915,200
static const size_t WS_WT1  = 57753600;                // bf16 [3][128][1600] 1,228,800
static const size_t WS_WT2  = 58982400;                // bf16 [64][128] 16,384
static const size_t WS_WT2G = 58998784;                // bf16 [64][64] 8,192
static const size_t WS_Y3   = 59006976;                // f32 [64][256][128] 8,388,608
static const size_t WS_Y4   = 67395584;                // f32 [64][256][64] 4,194,304
static const size_t WS_ST   = 71589888;                // f32 stats block
// stats block float offsets
#define ST_S9    0
#define ST_SUM2  16
#define ST_SQ2   80
#define ST_SUM3  144
#define ST_SQ3   272
#define ST_SUM4  400
#define ST_SQ4   464
#define ST_COUNT 528

__device__ __forceinline__ float bf2f(unsigned int u){
  return __uint_as_float(u << 16);
}
__device__ __forceinline__ unsigned short f2bf(float f){
  unsigned int u = __float_as_uint(f);
  u += 0x7fffu + ((u >> 16) & 1u);   // RNE
  return (unsigned short)(u >> 16);
}
__device__ __forceinline__ float lrelu(float x){ return fmaxf(x, 0.2f * x); }
__device__ __forceinline__ float wsum(float v){
  #pragma unroll
  for (int off = 32; off > 0; off >>= 1) v += __shfl_down(v, off, 64);
  return v;
}

typedef __attribute__((address_space(3))) unsigned int lds_uint_t;
typedef __attribute__((address_space(1))) const unsigned int glob_uint_t;
__device__ __forceinline__ void gl16(const void* g, void* l){
  __builtin_amdgcn_global_load_lds((glob_uint_t*)g, (lds_uint_t*)l, 16, 0, 0);
}

// ---- fused prologue: weight transforms + y2t pad zeroing + GCN1 aggregate/moments ----
// blocks 0..383: wt1 transform; 384..415: wt2; 416..431: wt2g; 432..495: zpad;
// 496..2095: gcn1 (n = (blk-496)*256 + tid)
__global__ __launch_bounds__(256) void k_pre(const float* __restrict__ cw1,
                                             const float* __restrict__ W2,
                                             const float* __restrict__ cw2,
                                             const float* __restrict__ x,
                                             unsigned short* __restrict__ wt1,
                                             unsigned short* __restrict__ wt2,
                                             unsigned short* __restrict__ wt2g,
                                             unsigned short* __restrict__ y2t,
                                             float* __restrict__ xa,
                                             float* __restrict__ S9){
  int blk = blockIdx.x;
  if (blk < 384){
    int k = blk >> 7, o = blk & 127;
    for (int c = threadIdx.x; c < 1600; c += 256)
      wt1[(size_t)(k * 128 + o) * 1600 + c] = f2bf(cw1[(size_t)(o * 1600 + c) * 3 + k]);
    return;
  } else if (blk < 416){
    int idx = ((blk - 384) << 8) + threadIdx.x;   // 8192
    wt2[idx] = f2bf(cw2[idx]);
    return;
  } else if (blk < 432){
    int idx = ((blk - 416) << 8) + threadIdx.x;   // 4096
    int f = idx >> 6, cc = idx & 63;
    wt2g[idx] = f2bf(W2[cc * 64 + f]);
    return;
  } else if (blk < 496){
    int b = blk - 432, tid = threadIdx.x;
    if (tid < 200){
      uint4 z = make_uint4(0,0,0,0);
      ((uint4*)(y2t + (size_t)b * 412800))[tid] = z;
      ((uint4*)(y2t + (size_t)b * 412800 + 257 * 1600))[tid] = z;
    }
    return;
  }
  // ---- gcn1 part ----
  int n = (blk - 496) * 256 + threadIdx.x;
  int j = n % J_;
  float dj  = (j == 0 || j == J_-1) ? 2.f : 3.f;
  float rdj = rsqrtf(dj);
  const float* xp = x + (size_t)n * 3;
  float wg = 1.f / dj;
  float a0 = xp[0]*wg, a1 = xp[1]*wg, a2 = xp[2]*wg;
  if (j > 0){
    float dm = (j == 1) ? 2.f : 3.f;  float w = rdj * rsqrtf(dm);
    a0 += xp[-3]*w; a1 += xp[-2]*w; a2 += xp[-1]*w;
  }
  if (j < J_-1){
    float dp = (j == J_-2) ? 2.f : 3.f;  float w = rdj * rsqrtf(dp);
    a0 += xp[3]*w; a1 += xp[4]*w; a2 += xp[5]*w;
  }
  float* xo = xa + (size_t)n * 3;
  xo[0] = a0; xo[1] = a1; xo[2] = a2;
  float p[9] = {a0, a1, a2, a0*a0, a0*a1, a0*a2, a1*a1, a1*a2, a2*a2};
  __shared__ float tmp[9][4];
  int wv = threadIdx.x >> 6, ln = threadIdx.x & 63;
  #pragma unroll
  for (int k = 0; k < 9; k++){ float s = wsum(p[k]); if (ln == 0) tmp[k][wv] = s; }
  __syncthreads();
  if (threadIdx.x < 9){
    int k = threadIdx.x;
    atomicAdd(S9 + k, tmp[k][0] + tmp[k][1] + tmp[k][2] + tmp[k][3]);
  }
}

// ---- GCN2 via MFMA: bf16 xas, single As, 2 barriers, grid 512;
//      scattered stores; fused BN1-param + BN2 stats (R13/R15 verified best) ----
#define H1SLICE(ph, js) do { \
  int js_ = (js); \
  _Pragma("unroll") \
  for (int i_ = 0; i_ < 16; i_++){ \
    const unsigned short* xp_ = xas + ((wl0 + i_) * 25 + js_) * 3; \
    float x0_ = bf2f(xp_[0]), x1_ = bf2f(xp_[1]), x2_ = bf2f(xp_[2]); \
    h[ph][i_] = lrelu(fmaf(sS, fmaf(x0_, w0c, fmaf(x1_, w1c, x2_*w2c)), tT)); \
  } } while(0)

#define AGGW(pm, pc, pp) do { \
  _Pragma("unroll") \
  for (int i_ = 0; i_ < 16; i_++){ \
    float a_ = wgm*h[pm][i_] + wgs*h[pc][i_] + wgp*h[pp][i_]; \
    int row_ = wl0 + i_; \
    *(unsigned short*)(As + row_*128 + ((((lane>>3)) ^ (row_&7))<<4) + ((lane&7)<<1)) = f2bf(a_); \
  } } while(0)

__global__ __launch_bounds__(256) void k_gcn2m(const float* __restrict__ xa,
                                               const float* __restrict__ W1,
                                               const float* __restrict__ S9,
                                               const float* __restrict__ b1,
                                               const float* __restrict__ g1,
                                               const float* __restrict__ be1,
                                               const float* __restrict__ b2,
                                               const unsigned short* __restrict__ wt2g,
                                               unsigned short* __restrict__ y2t,
                                               float* __restrict__ sum2,
                                               float* __restrict__ sq2){
  __shared__ unsigned short xas[4800]; // [64 l][25 j][3 d] bf16 (9.6KB)
  __shared__ float prm[384];           // W1(192) s1(64) t1(64) b2(64)
  __shared__ char As[8192];            // agg tile [64 l][64 cc] bf16, swizzled
  __shared__ char Bs[8192];            // wt2g tile [64 f][64 cc] bf16, swizzled
  int blk = blockIdx.x;                // 512 = ((b*4)+lq)*2 + jh
  int jh = blk & 1;
  int lq = (blk >> 1) & 3;
  int b  = blk >> 3;
  int l0 = lq << 6;
  int tid = threadIdx.x;
  int w = tid >> 6, lane = tid & 63;

  const float* xsrc = xa + (size_t)(b * 256 + l0) * 75;
  #pragma unroll
  for (int i = 0; i < 5; i++){
    int idx = tid + (i << 8);
    if (idx < 1200){
      float4 v = ((const float4*)xsrc)[idx];
      uint2 u;
      u.x = (unsigned)f2bf(v.x) | ((unsigned)f2bf(v.y) << 16);
      u.y = (unsigned)f2bf(v.z) | ((unsigned)f2bf(v.w) << 16);
      ((uint2*)xas)[idx] = u;
    }
  }
  if (tid < 192) prm[tid] = W1[tid];
  else if (tid < 256) prm[tid + 128] = b2[tid - 192];   // prm[320..383] = b2
  if (tid < 64){
    float inv = 1.f / (float)NN_;
    float m0 = S9[0]*inv, m1 = S9[1]*inv, m2 = S9[2]*inv;
    float C00 = S9[3]*inv - m0*m0, C01 = S9[4]*inv - m0*m1, C02 = S9[5]*inv - m0*m2;
    float C11 = S9[6]*inv - m1*m1, C12 = S9[7]*inv - m1*m2, C22 = S9[8]*inv - m2*m2;
    float w0 = W1[tid], w1 = W1[64+tid], w2 = W1[128+tid];
    float mean = m0*w0 + m1*w1 + m2*w2 + b1[tid];
    float var  = w0*w0*C00 + w1*w1*C11 + w2*w2*C22
               + 2.f*(w0*w1*C01 + w0*w2*C02 + w1*w2*C12);
    float s = g1[tid] * rsqrtf(var + EPSV);
    prm[192 + tid] = s;
    prm[256 + tid] = be1[tid] - s*mean + s*b1[tid];
  }
  #pragma unroll
  for (int i = 0; i < 2; i++){
    int r = (w << 4) + (i << 3) + (lane >> 3);
    int cblk = lane & 7;
    gl16(wt2g + (size_t)r * 64 + (((cblk ^ (r & 7))) << 3),
         Bs + (w << 11) + (i << 10));
  }
  __syncthreads();   // prologue barrier

  float w0c = prm[lane], w1c = prm[64 + lane], w2c = prm[128 + lane];
  float sS = prm[192 + lane], tT = prm[256 + lane];
  int wm = w >> 1, wn = w & 1;
  int m0 = (wm << 5) + (lane & 15);
  int n0 = (wn << 5) + (lane & 15);
  int kg = lane >> 4;
  float bias0 = prm[320 + n0], bias1 = prm[320 + n0 + 16];
  int wl0 = w << 4;

  float h[3][16];
  int J0 = jh ? 12 : 0;
  int NJ = jh ? 13 : 12;
  #pragma unroll
  for (int i = 0; i < 16; i++) h[2][i] = 0.f;
  H1SLICE(0, J0);
  if (J0 > 0) H1SLICE(2, J0 - 1);

  float ss0 = 0.f, ss1 = 0.f, qq0 = 0.f, qq1 = 0.f;

  #pragma unroll
  for (int jj = 0; jj < 13; jj++){
    if (jj >= NJ) break;
    int j = J0 + jj;
    if (j + 1 <= 24){
      switch ((jj + 1) % 3){
        case 0: H1SLICE(0, j + 1); break;
        case 1: H1SLICE(1, j + 1); break;
        case 2: H1SLICE(2, j + 1); break;
      }
    }
    float dj  = (j == 0 || j == 24) ? 2.f : 3.f;
    float rdj = rsqrtf(dj);
    float wgs = 1.f / dj;
    float wgm = (j > 0)  ? rdj * rsqrtf((j == 1)  ? 2.f : 3.f) : 0.f;
    float wgp = (j < 24) ? rdj * rsqrtf((j == 23) ? 2.f : 3.f) : 0.f;
    switch (jj % 3){
      case 0: AGGW(2, 0, 1); break;
      case 1: AGGW(0, 1, 2); break;
      case 2: AGGW(1, 2, 0); break;
    }
    __syncthreads();   // As visible
    f32x4 acc[2][2] = {};
    #pragma unroll
    for (int ks = 0; ks < 2; ks++){
      int kb = kg + (ks << 2);
      short8 a0 = *(const short8*)(As + (m0 << 7)        + ((kb ^ (m0 & 7)) << 4));
      short8 a1 = *(const short8*)(As + ((m0 + 16) << 7) + ((kb ^ (m0 & 7)) << 4));
      short8 b0 = *(const short8*)(Bs + (n0 << 7)        + ((kb ^ (n0 & 7)) << 4));
      short8 b1 = *(const short8*)(Bs + ((n0 + 16) << 7) + ((kb ^ (n0 & 7)) << 4));
      acc[0][0] = __builtin_amdgcn_mfma_f32_16x16x32_bf16(a0, b0, acc[0][0], 0, 0, 0);
      acc[0][1] = __builtin_amdgcn_mfma_f32_16x16x32_bf16(a0, b1, acc[0][1], 0, 0, 0);
      acc[1][0] = __builtin_amdgcn_mfma_f32_16x16x32_bf16(a1, b0, acc[1][0], 0, 0, 0);
      acc[1][1] = __builtin_amdgcn_mfma_f32_16x16x32_bf16(a1, b1, acc[1][1], 0, 0, 0);
    }
    __syncthreads();   // As reads done -> reusable next j
    // epilogue: bias + stats partials + scattered bf16 stores (R4-proven)
    int rowb = (wm << 5) + ((lane >> 4) << 2);
    #pragma unroll
    for (int mi = 0; mi < 2; mi++){
      #pragma unroll
      for (int ni = 0; ni < 2; ni++){
        float bias = ni ? bias1 : bias0;
        int f = n0 + (ni << 4);
        #pragma unroll
        for (int r = 0; r < 4; r++){
          float v = acc[mi][ni][r] + bias;
          if (ni){ ss1 += v; qq1 += v * v; } else { ss0 += v; qq0 += v * v; }
          int rl = rowb + (mi << 4) + r;
          y2t[(size_t)(b * 258 + l0 + rl + 1) * 1600 + j * 64 + f] = f2bf(v);
        }
      }
    }
  }
  ss0 += __shfl_xor(ss0, 16, 64); ss0 += __shfl_xor(ss0, 32, 64);
  ss1 += __shfl_xor(ss1, 16, 64); ss1 += __shfl_xor(ss1, 32, 64);
  qq0 += __shfl_xor(qq0, 16, 64); qq0 += __shfl_xor(qq0, 32, 64);
  qq1 += __shfl_xor(qq1, 16, 64); qq1 += __shfl_xor(qq1, 32, 64);
  if ((lane >> 4) == 0){
    atomicAdd(sum2 + n0, ss0);      atomicAdd(sq2 + n0, qq0);
    atomicAdd(sum2 + n0 + 16, ss1); atomicAdd(sq2 + n0 + 16, qq1);
  }
}

// ---- BN2+lrelu in place on y2t (pads stay zero) + fused BN2-param computation ----
__global__ __launch_bounds__(256) void k_bnapp2(unsigned short* __restrict__ y2t,
                                                const float* __restrict__ sum2,
                                                const float* __restrict__ sq2,
                                                const float* __restrict__ g2,
                                                const float* __restrict__ be2){
  __shared__ float scL[64], shL[64];
  int tid = threadIdx.x;
  if (tid < 64){
    float inv = 1.f / (float)NN_;
    float mean = sum2[tid] * inv;
    float var  = sq2[tid] * inv - mean * mean;
    float s = g2[tid] * rsqrtf(var + EPSV);
    scL[tid] = s; shL[tid] = be2[tid] - s * mean;
  }
  __syncthreads();
  for (unsigned idx = blockIdx.x * 256 + tid; idx < 3276800u; idx += 524288u){
    unsigned b = idx / 51200u;
    unsigned rem = idx - b * 51200u;
    unsigned l = rem / 200u;
    unsigned cg = rem - l * 200u;
    uint4* p = (uint4*)y2t + ((size_t)b * 258 + l + 1) * 200 + cg;
    unsigned f0 = (cg << 3) & 63u;
    float scs[8], shs[8];
    #pragma unroll
    for (int i = 0; i < 8; i++){ scs[i] = scL[f0 + i]; shs[i] = shL[f0 + i]; }
    uint4 v = *p;
    unsigned vv[4] = {v.x,v.y,v.z,v.w};
    unsigned r[4];
    #pragma unroll
    for (int i = 0; i < 4; i++){
      float lo = bf2f(vv[i] & 0xffffu);
      float hi = bf2f(vv[i] >> 16);
      lo = lrelu(fmaf(scs[2*i],   lo, shs[2*i]));
      hi = lrelu(fmaf(scs[2*i+1], hi, shs[2*i+1]));
      r[i] = (unsigned)f2bf(lo) | (((unsigned)f2bf(hi)) << 16);
    }
    *p = make_uint4(r[0],r[1],r[2],r[3]);
  }
}

// ---- conv1 as MFMA GEMM + fused stats3; t-order (cc outer, k inner) for L2 tap reuse ----
#define NT_ 75
__global__ __launch_bounds__(256) void k_conv1(const unsigned short* __restrict__ y2t,
                                               const unsigned short* __restrict__ wt1,
                                               const float* __restrict__ cb1,
                                               float* __restrict__ y3,
                                               float* __restrict__ sum3,
                                               float* __restrict__ sq3){
  __shared__ char smem[32768];
  // XCD-aware swizzle: og/lq/b siblings land on the same XCD for L2 dedup
  int bid = blockIdx.x;          // 512
  int blk = ((bid & 7) << 6) | (bid >> 3);
  int b  = blk >> 3;
  int lq = (blk >> 1) & 3;
  int og = blk & 1;
  int l0 = lq << 6;
  int tid = threadIdx.x;
  int w = tid >> 6, lane = tid & 63;
  int wm = w >> 1, wn = w & 1;
  const unsigned short* y2b = y2t + (size_t)b * 412800;
  const unsigned short* wtb = wt1 + (size_t)og * 64 * 1600;

  int rs = (w << 4) + (lane >> 3);
  int cblk = lane & 7;
  int m0 = (wm << 5) + (lane & 15);
  int n0 = (wn << 5) + (lane & 15);
  int kg = lane >> 4;

  f32x4 acc[2][2] = {};

  auto stage = [&](int t, int buf){
    int cc6 = (t * 0x5556) >> 16;          // t / 3 for t < 75
    int k   = t - cc6 * 3;
    int cc  = cc6 << 6;
    const unsigned short* wk = wtb + (size_t)k * 204800;
    #pragma unroll
    for (int i = 0; i < 2; i++){
      int r = rs + (i << 3);
      int sw = (cblk ^ (r & 7)) << 3;
      gl16(y2b + (size_t)(l0 + r + k) * 1600 + cc + sw,
           smem + buf * 16384 + (w << 11) + (i << 10));
      gl16(wk + (size_t)r * 1600 + cc + sw,
           smem + buf * 16384 + 8192 + (w << 11) + (i << 10));
    }
  };

  stage(0, 0);
  __syncthreads();
  #pragma unroll 2
  for (int t = 0; t < NT_; ++t){
    int buf = t & 1;
    if (t + 1 < NT_) stage(t + 1, buf ^ 1);
    const char* Ab = smem + buf * 16384;
    const char* Bb = Ab + 8192;
    #pragma unroll
    for (int ks = 0; ks < 2; ks++){
      int kb = kg + (ks << 2);
      short8 a0 = *(const short8*)(Ab + (m0 << 7)        + ((kb ^ (m0 & 7)) << 4));
      short8 a1 = *(const short8*)(Ab + ((m0 + 16) << 7) + ((kb ^ (m0 & 7)) << 4));
      short8 b0 = *(const short8*)(Bb + (n0 << 7)        + ((kb ^ (n0 & 7)) << 4));
      short8 b1 = *(const short8*)(Bb + ((n0 + 16) << 7) + ((kb ^ (n0 & 7)) << 4));
      acc[0][0] = __builtin_amdgcn_mfma_f32_16x16x32_bf16(a0, b0, acc[0][0], 0, 0, 0);
      acc[0][1] = __builtin_amdgcn_mfma_f32_16x16x32_bf16(a0, b1, acc[0][1], 0, 0, 0);
      acc[1][0] = __builtin_amdgcn_mfma_f32_16x16x32_bf16(a1, b0, acc[1][0], 0, 0, 0);
      acc[1][1] = __builtin_amdgcn_mfma_f32_16x16x32_bf16(a1, b1, acc[1][1], 0, 0, 0);
    }
    __syncthreads();
  }

  int colb = (og << 6) + n0;
  int rowb = l0 + (wm << 5) + ((lane >> 4) << 2);
  float ss0 = 0.f, ss1 = 0.f, qq0 = 0.f, qq1 = 0.f;
  #pragma unroll
  for (int mi = 0; mi < 2; mi++){
    #pragma unroll
    for (int ni = 0; ni < 2; ni++){
      int col = colb + (ni << 4);
      float bias = cb1[col];
      #pragma unroll
      for (int r = 0; r < 4; r++){
        float v = acc[mi][ni][r] + bias;
        if (ni){ ss1 += v; qq1 += v * v; } else { ss0 += v; qq0 += v * v; }
        y3[(size_t)((b << 8) + rowb + (mi << 4) + r) * 128 + col] = v;
      }
    }
  }
  ss0 += __shfl_xor(ss0, 16, 64); ss0 += __shfl_xor(ss0, 32, 64);
  ss1 += __shfl_xor(ss1, 16, 64); ss1 += __shfl_xor(ss1, 32, 64);
  qq0 += __shfl_xor(qq0, 16, 64); qq0 += __shfl_xor(qq0, 32, 64);
  qq1 += __shfl_xor(qq1, 16, 64); qq1 += __shfl_xor(qq1, 32, 64);
  if ((lane >> 4) == 0){
    atomicAdd(sum3 + colb, ss0);      atomicAdd(sq3 + colb, qq0);
    atomicAdd(sum3 + colb + 16, ss1); atomicAdd(sq3 + colb + 16, qq1);
  }
}

// ---- conv2 MFMA + fused BN3-param compute + BN3/lrelu on A-staging + fused stats4 ----
__global__ __launch_bounds__(256) void k_conv2(const float* __restrict__ y3,
                                               const float* __restrict__ sum3,
                                               const float* __restrict__ sq3,
                                               const float* __restrict__ cg1,
                                               const float* __restrict__ cbe1,
                                               const unsigned short* __restrict__ wt2,
                                               const float* __restrict__ cb2,
                                               float* __restrict__ y4,
                                               float* __restrict__ sum4,
                                               float* __restrict__ sq4){
  __shared__ char smem[32768];
  __shared__ float sc3s[128], sh3s[128];
  int blk = blockIdx.x;          // 256 = 64b * 4lq
  int b = blk >> 2, lq = blk & 3;
  int l0 = lq << 6;
  int tid = threadIdx.x;
  int w = tid >> 6, lane = tid & 63;
  int wm = w >> 1, wn = w & 1;
  #pragma unroll
  for (int i = 0; i < 4; i++){
    int r = (w << 4) + (i << 2) + (lane >> 4);
    int sw = (((lane & 15) ^ (r & 7)) << 3);
    gl16(wt2 + (size_t)r * 128 + sw, smem + 16384 + (w << 12) + (i << 10));
  }
  if (tid < 128){
    float inv = 1.f / (float)MM_;
    float mean = sum3[tid] * inv;
    float var  = sq3[tid] * inv - mean * mean;
    float s = cg1[tid] * rsqrtf(var + EPSV);
    sc3s[tid] = s; sh3s[tid] = cbe1[tid] - s * mean;
  }
  __syncthreads();
  #pragma unroll
  for (int i = 0; i < 4; i++){
    int idx = tid + (i << 8);
    int r = idx >> 4, s = idx & 15;
    const float* src = y3 + (size_t)((b << 8) + l0 + r) * 128 + (s << 3);
    float4 v0 = *(const float4*)(src);
    float4 v1 = *(const float4*)(src + 4);
    float4 c0 = *(const float4*)(sc3s + (s << 3));
    float4 c1 = *(const float4*)(sc3s + (s << 3) + 4);
    float4 h0 = *(const float4*)(sh3s + (s << 3));
    float4 h1 = *(const float4*)(sh3s + (s << 3) + 4);
    uint4 u;
    u.x = (unsigned)f2bf(lrelu(fmaf(c0.x, v0.x, h0.x))) |
          ((unsigned)f2bf(lrelu(fmaf(c0.y, v0.y, h0.y))) << 16);
    u.y = (unsigned)f2bf(lrelu(fmaf(c0.z, v0.z, h0.z))) |
          ((unsigned)f2bf(lrelu(fmaf(c0.w, v0.w, h0.w))) << 16);
    u.z = (unsigned)f2bf(lrelu(fmaf(c1.x, v1.x, h1.x))) |
          ((unsigned)f2bf(lrelu(fmaf(c1.y, v1.y, h1.y))) << 16);
    u.w = (unsigned)f2bf(lrelu(fmaf(c1.z, v1.z, h1.z))) |
          ((unsigned)f2bf(lrelu(fmaf(c1.w, v1.w, h1.w))) << 16);
    *(uint4*)(smem + r * 256 + ((s ^ (r & 7)) << 4)) = u;
  }
  __syncthreads();
  f32x4 acc[2][2] = {};
  int m0 = (wm << 5) + (lane & 15);
  int n0 = (wn << 5) + (lane & 15);
  int kg = lane >> 4;
  const char* Ab = smem;
  const char* Bb = smem + 16384;
  #pragma unroll
  for (int ks = 0; ks < 4; ks++){
    int kb = kg + (ks << 2);
    short8 a0 = *(const short8*)(Ab + (m0 << 8)        + ((kb ^ (m0 & 7)) << 4));
    short8 a1 = *(const short8*)(Ab + ((m0 + 16) << 8) + ((kb ^ (m0 & 7)) << 4));
    short8 b0 = *(const short8*)(Bb + (n0 << 8)        + ((kb ^ (n0 & 7)) << 4));
    short8 b1 = *(const short8*)(Bb + ((n0 + 16) << 8) + ((kb ^ (n0 & 7)) << 4));
    acc[0][0] = __builtin_amdgcn_mfma_f32_16x16x32_bf16(a0, b0, acc[0][0], 0, 0, 0);
    acc[0][1] = __builtin_amdgcn_mfma_f32_16x16x32_bf16(a0, b1, acc[0][1], 0, 0, 0);
    acc[1][0] = __builtin_amdgcn_mfma_f32_16x16x32_bf16(a1, b0, acc[1][0], 0, 0, 0);
    acc[1][1] = __builtin_amdgcn_mfma_f32_16x16x32_bf16(a1, b1, acc[1][1], 0, 0, 0);
  }
  int rowb = l0 + (wm << 5) + ((lane >> 4) << 2);
  float ss0 = 0.f, ss1 = 0.f, qq0 = 0.f, qq1 = 0.f;
  #pragma unroll
  for (int mi = 0; mi < 2; mi++){
    #pragma unroll
    for (int ni = 0; ni < 2; ni++){
      int f = n0 + (ni << 4);
      float bias = cb2[f];
      #pragma unroll
      for (int r = 0; r < 4; r++){
        float v = acc[mi][ni][r] + bias;
        if (ni){ ss1 += v; qq1 += v * v; } else { ss0 += v; qq0 += v * v; }
        y4[(size_t)((b << 8) + rowb + (mi << 4) + r) * 64 + f] = v;
      }
    }
  }
  ss0 += __shfl_xor(ss0, 16, 64); ss0 += __shfl_xor(ss0, 32, 64);
  ss1 += __shfl_xor(ss1, 16, 64); ss1 += __shfl_xor(ss1, 32, 64);
  qq0 += __shfl_xor(qq0, 16, 64); qq0 += __shfl_xor(qq0, 32, 64);
  qq1 += __shfl_xor(qq1, 16, 64); qq1 += __shfl_xor(qq1, 32, 64);
  if ((lane >> 4) == 0){
    atomicAdd(sum4 + n0, ss0);      atomicAdd(sq4 + n0, qq0);
    atomicAdd(sum4 + n0 + 16, ss1); atomicAdd(sq4 + n0 + 16, qq1);
  }
}

// ---- final: out = lrelu(bn4(y4)) + fused BN4-param compute ----
__global__ __launch_bounds__(256) void k_final(const float* __restrict__ y4,
                                               const float* __restrict__ sum4,
                                               const float* __restrict__ sq4,
                                               const float* __restrict__ cg2,
                                               const float* __restrict__ cbe2,
                                               float* __restrict__ out){
  __shared__ float sc4s[64], sh4s[64];
  int tid = threadIdx.x;
  if (tid < 64){
    float inv = 1.f / (float)MM_;
    float mean = sum4[tid] * inv;
    float var  = sq4[tid] * inv - mean * mean;
    float s = cg2[tid] * rsqrtf(var + EPSV);
    sc4s[tid] = s; sh4s[tid] = cbe2[tid] - s * mean;
  }
  __syncthreads();
  unsigned q = blockIdx.x * 256 + tid;
  unsigned f0 = (q & 15) << 2;
  float4 v = ((const float4*)y4)[q];
  float4 sc = *(const float4*)(sc4s + f0);
  float4 sh = *(const float4*)(sh4s + f0);
  v.x = lrelu(fmaf(sc.x, v.x, sh.x));
  v.y = lrelu(fmaf(sc.y, v.y, sh.y));
  v.z = lrelu(fmaf(sc.z, v.z, sh.z));
  v.w = lrelu(fmaf(sc.w, v.w, sh.w));
  ((float4*)out)[q] = v;
}

extern "C" void kernel_launch(void* const* d_in, const int* in_sizes, int n_in,
                              void* d_out, int out_size, void* d_ws, size_t ws_size,
                              hipStream_t stream){
  const float* x    = (const float*)d_in[0];
  const float* W1   = (const float*)d_in[4];
  const float* b1   = (const float*)d_in[5];
  const float* g1   = (const float*)d_in[6];
  const float* be1  = (const float*)d_in[7];
  const float* W2   = (const float*)d_in[8];
  const float* b2   = (const float*)d_in[9];
  const float* g2   = (const float*)d_in[10];
  const float* be2  = (const float*)d_in[11];
  const float* cw1  = (const float*)d_in[12];
  const float* cb1  = (const float*)d_in[13];
  const float* cg1  = (const float*)d_in[14];
  const float* cbe1 = (const float*)d_in[15];
  const float* cw2  = (const float*)d_in[16];
  const float* cb2  = (const float*)d_in[17];
  const float* cg2  = (const float*)d_in[18];
  const float* cbe2 = (const float*)d_in[19];

  char* ws = (char*)d_ws;
  unsigned short* y2t  = (unsigned short*)(ws + WS_Y2T);
  float* xa            = (float*)(ws + WS_XA);
  unsigned short* wt1  = (unsigned short*)(ws + WS_WT1);
  unsigned short* wt2  = (unsigned short*)(ws + WS_WT2);
  unsigned short* wt2g = (unsigned short*)(ws + WS_WT2G);
  float* y3            = (float*)(ws + WS_Y3);
  float* y4            = (float*)(ws + WS_Y4);
  float* st            = (float*)(ws + WS_ST);

  if (ws_size < WS_ST + ST_COUNT * 4) return;

  hipMemsetAsync(st, 0, ST_COUNT * 4, stream);
  k_pre   <<<2096, 256, 0, stream>>>(cw1, W2, cw2, x, wt1, wt2, wt2g, y2t,
                                     xa, st + ST_S9);
  k_gcn2m <<<512, 256, 0, stream>>>(xa, W1, st + ST_S9, b1, g1, be1, b2, wt2g,
                                    y2t, st + ST_SUM2, st + ST_SQ2);
  k_bnapp2<<<2048, 256, 0, stream>>>(y2t, st + ST_SUM2, st + ST_SQ2, g2, be2);
  k_conv1 <<<512, 256, 0, stream>>>(y2t, wt1, cb1, y3, st + ST_SUM3, st + ST_SQ3);
  k_conv2 <<<256, 256, 0, stream>>>(y3, st + ST_SUM3, st + ST_SQ3, cg1, cbe1,
                                    wt2, cb2, y4, st + ST_SUM4, st + ST_SQ4);
  k_final <<<1024, 256, 0, stream>>>(y4, st + ST_SUM4, st + ST_SQ4, cg2, cbe2,
                                     (float*)d_out);
}

// Round 18
// 166.527 us; speedup vs baseline: 1.1447x; 1.0012x over previous
//
#include <hip/hip_runtime.h>
#include <stdint.h>

#define B_ 64
#define F2_ 256
#define J_ 25
#define FILT_ 64
#define C1_ 1600   // J*FILT
#define O1_ 128
#define NN_ 409600 // B*F*J
#define MM_ 16384  // B*F
#define EPSV 1e-5f

typedef short short8 __attribute__((ext_vector_type(8)));
typedef float f32x4 __attribute__((ext_vector_type(4)));

// ---- workspace layout (bytes) ----
static const size_t WS_Y2T  = 0;                       // 52,838,400
static const size_t WS_XA   = 52838400;                // f32 [NN][3] 4,915,200
static const size_t WS_WT1  = 57753600;                // bf16 [3][128][1600] 1,228,800
static const size_t WS_WT2  = 58982400;                // bf16 [64][128] 16,384
static const size_t WS_WT2G = 58998784;                // bf16 [64][64] 8,192
static const size_t WS_Y3   = 59006976;                // f32 [64][256][128] 8,388,608
static const size_t WS_Y4   = 67395584;                // f32 [64][256][64] 4,194,304
static const size_t WS_ST   = 71589888;                // f32 stats block
#define ST_S9    0
#define ST_SUM2  16
#define ST_SQ2   80
#define ST_SUM3  144
#define ST_SQ3   272
#define ST_SUM4  400
#define ST_SQ4   464
#define ST_COUNT 528

__device__ __forceinline__ float bf2f(unsigned int u){
  return __uint_as_float(u << 16);
}
__device__ __forceinline__ float bfhi(unsigned int u){
  return __uint_as_float(u & 0xffff0000u);
}
__device__ __forceinline__ unsigned short f2bf(float f){
  unsigned int u = __float_as_uint(f);
  u += 0x7fffu + ((u >> 16) & 1u);   // RNE
  return (unsigned short)(u >> 16);
}
__device__ __forceinline__ float lrelu(float x){ return fmaxf(x, 0.2f * x); }
__device__ __forceinline__ float wsum(float v){
  #pragma unroll
  for (int off = 32; off > 0; off >>= 1) v += __shfl_down(v, off, 64);
  return v;
}

typedef __attribute__((address_space(3))) unsigned int lds_uint_t;
typedef __attribute__((address_space(1))) const unsigned int glob_uint_t;
__device__ __forceinline__ void gl16(const void* g, void* l){
  __builtin_amdgcn_global_load_lds((glob_uint_t*)g, (lds_uint_t*)l, 16, 0, 0);
}

// ---- fused prologue: weight transforms + y2t pad zeroing + GCN1 aggregate/moments ----
__global__ __launch_bounds__(256) void k_pre(const float* __restrict__ cw1,
                                             const float* __restrict__ W2,
                                             const float* __restrict__ cw2,
                                             const float* __restrict__ x,
                                             unsigned short* __restrict__ wt1,
                                             unsigned short* __restrict__ wt2,
                                             unsigned short* __restrict__ wt2g,
                                             unsigned short* __restrict__ y2t,
                                             float* __restrict__ xa,
                                             float* __restrict__ S9){
  int blk = blockIdx.x;
  if (blk < 384){
    int k = blk >> 7, o = blk & 127;
    for (int c = threadIdx.x; c < 1600; c += 256)
      wt1[(size_t)(k * 128 + o) * 1600 + c] = f2bf(cw1[(size_t)(o * 1600 + c) * 3 + k]);
    return;
  } else if (blk < 416){
    int idx = ((blk - 384) << 8) + threadIdx.x;   // 8192
    wt2[idx] = f2bf(cw2[idx]);
    return;
  } else if (blk < 432){
    int idx = ((blk - 416) << 8) + threadIdx.x;   // 4096
    int f = idx >> 6, cc = idx & 63;
    wt2g[idx] = f2bf(W2[cc * 64 + f]);
    return;
  } else if (blk < 496){
    int b = blk - 432, tid = threadIdx.x;
    if (tid < 200){
      uint4 z = make_uint4(0,0,0,0);
      ((uint4*)(y2t + (size_t)b * 412800))[tid] = z;
      ((uint4*)(y2t + (size_t)b * 412800 + 257 * 1600))[tid] = z;
    }
    return;
  }
  int n = (blk - 496) * 256 + threadIdx.x;
  int j = n % J_;
  float dj  = (j == 0 || j == J_-1) ? 2.f : 3.f;
  float rdj = rsqrtf(dj);
  const float* xp = x + (size_t)n * 3;
  float wg = 1.f / dj;
  float a0 = xp[0]*wg, a1 = xp[1]*wg, a2 = xp[2]*wg;
  if (j > 0){
    float dm = (j == 1) ? 2.f : 3.f;  float w = rdj * rsqrtf(dm);
    a0 += xp[-3]*w; a1 += xp[-2]*w; a2 += xp[-1]*w;
  }
  if (j < J_-1){
    float dp = (j == J_-2) ? 2.f : 3.f;  float w = rdj * rsqrtf(dp);
    a0 += xp[3]*w; a1 += xp[4]*w; a2 += xp[5]*w;
  }
  float* xo = xa + (size_t)n * 3;
  xo[0] = a0; xo[1] = a1; xo[2] = a2;
  float p[9] = {a0, a1, a2, a0*a0, a0*a1, a0*a2, a1*a1, a1*a2, a2*a2};
  __shared__ float tmp[9][4];
  int wv = threadIdx.x >> 6, ln = threadIdx.x & 63;
  #pragma unroll
  for (int k = 0; k < 9; k++){ float s = wsum(p[k]); if (ln == 0) tmp[k][wv] = s; }
  __syncthreads();
  if (threadIdx.x < 9){
    int k = threadIdx.x;
    atomicAdd(S9 + k, tmp[k][0] + tmp[k][1] + tmp[k][2] + tmp[k][3]);
  }
}

// ---- GCN2 via MFMA: j-major xas transpose -> 6x ds_read_b128 per H-slice (was 48x u16);
//      B-fragments hoisted to registers; fused BN1-param + BN2 stats; scattered stores ----
// HCOMP: row i_ elements e=3i_+d of 48 packed bf16 in lv[24] uints (all indices static)
#define HCOMP(ph, js_) do { \
  const uint4* bp_ = (const uint4*)((const char*)xas + (js_) * 384 + w * 96); \
  unsigned lv[24]; \
  _Pragma("unroll") \
  for (int k_ = 0; k_ < 6; k_++){ \
    uint4 t_ = bp_[k_]; \
    lv[4*k_] = t_.x; lv[4*k_+1] = t_.y; lv[4*k_+2] = t_.z; lv[4*k_+3] = t_.w; \
  } \
  _Pragma("unroll") \
  for (int i_ = 0; i_ < 16; i_++){ \
    int q0_ = (3 * i_) >> 1; \
    float x0_, x1_, x2_; \
    if ((i_ & 1) == 0){ x0_ = bf2f(lv[q0_] & 0xffffu); x1_ = bfhi(lv[q0_]); x2_ = bf2f(lv[q0_+1] & 0xffffu); } \
    else              { x0_ = bfhi(lv[q0_]); x1_ = bf2f(lv[q0_+1] & 0xffffu); x2_ = bfhi(lv[q0_+1]); } \
    h[ph][i_] = lrelu(fmaf(sS, fmaf(x0_, w0c, fmaf(x1_, w1c, x2_*w2c)), tT)); \
  } } while(0)

#define AGGW(pm, pc, pp) do { \
  _Pragma("unroll") \
  for (int i_ = 0; i_ < 16; i_++){ \
    float a_ = wgm*h[pm][i_] + wgs*h[pc][i_] + wgp*h[pp][i_]; \
    int row_ = wl0 + i_; \
    *(unsigned short*)(As + row_*128 + ((((lane>>3)) ^ (row_&7))<<4) + ((lane&7)<<1)) = f2bf(a_); \
  } } while(0)

__global__ __launch_bounds__(256) void k_gcn2m(const float* __restrict__ xa,
                                               const float* __restrict__ W1,
                                               const float* __restrict__ S9,
                                               const float* __restrict__ b1,
                                               const float* __restrict__ g1,
                                               const float* __restrict__ be1,
                                               const float* __restrict__ b2,
                                               const unsigned short* __restrict__ wt2g,
                                               unsigned short* __restrict__ y2t,
                                               float* __restrict__ sum2,
                                               float* __restrict__ sq2){
  __shared__ unsigned short xlin[4800]; // [64 l][25 j][3 d] bf16 staging
  __shared__ unsigned short xas[4800];  // [25 j][64 l][3 d] bf16 (j-major)
  __shared__ float prm[384];            // W1(192) s1(64) t1(64) b2(64)
  __shared__ char As[8192];             // agg tile [64 l][64 cc] bf16, swizzled
  __shared__ char Bs[8192];             // wt2g tile [64 f][64 cc] bf16, swizzled
  int blk = blockIdx.x;                 // 512 = ((b*4)+lq)*2 + jh
  int jh = blk & 1;
  int lq = (blk >> 1) & 3;
  int b  = blk >> 3;
  int l0 = lq << 6;
  int tid = threadIdx.x;
  int w = tid >> 6, lane = tid & 63;

  const float* xsrc = xa + (size_t)(b * 256 + l0) * 75;
  #pragma unroll
  for (int i = 0; i < 5; i++){
    int idx = tid + (i << 8);
    if (idx < 1200){
      float4 v = ((const float4*)xsrc)[idx];
      uint2 u;
      u.x = (unsigned)f2bf(v.x) | ((unsigned)f2bf(v.y) << 16);
      u.y = (unsigned)f2bf(v.z) | ((unsigned)f2bf(v.w) << 16);
      ((uint2*)xlin)[idx] = u;
    }
  }
  if (tid < 192) prm[tid] = W1[tid];
  else if (tid < 256) prm[tid + 128] = b2[tid - 192];   // prm[320..383] = b2
  if (tid < 64){
    float inv = 1.f / (float)NN_;
    float m0 = S9[0]*inv, m1 = S9[1]*inv, m2 = S9[2]*inv;
    float C00 = S9[3]*inv - m0*m0, C01 = S9[4]*inv - m0*m1, C02 = S9[5]*inv - m0*m2;
    float C11 = S9[6]*inv - m1*m1, C12 = S9[7]*inv - m1*m2, C22 = S9[8]*inv - m2*m2;
    float w0 = W1[tid], w1 = W1[64+tid], w2 = W1[128+tid];
    float mean = m0*w0 + m1*w1 + m2*w2 + b1[tid];
    float var  = w0*w0*C00 + w1*w1*C11 + w2*w2*C22
               + 2.f*(w0*w1*C01 + w0*w2*C02 + w1*w2*C12);
    float s = g1[tid] * rsqrtf(var + EPSV);
    prm[192 + tid] = s;
    prm[256 + tid] = be1[tid] - s*mean + s*b1[tid];
  }
  #pragma unroll
  for (int i = 0; i < 2; i++){
    int r = (w << 4) + (i << 3) + (lane >> 3);
    int cblk = lane & 7;
    gl16(wt2g + (size_t)r * 64 + (((cblk ^ (r & 7))) << 3),
         Bs + (w << 11) + (i << 10));
  }
  __syncthreads();   // xlin/prm/Bs ready

  // transpose xlin [l][j][d] -> xas [j][l][d]
  #pragma unroll
  for (int t = 0; t < 7; t++){
    int p = tid + (t << 8);
    if (p < 1600){
      int js = p >> 6, l = p & 63;
      int si = l * 75 + js * 3;
      int di = js * 192 + l * 3;
      xas[di]     = xlin[si];
      xas[di + 1] = xlin[si + 1];
      xas[di + 2] = xlin[si + 2];
    }
  }

  float w0c = prm[lane], w1c = prm[64 + lane], w2c = prm[128 + lane];
  float sS = prm[192 + lane], tT = prm[256 + lane];
  int wm = w >> 1, wn = w & 1;
  int m0 = (wm << 5) + (lane & 15);
  int n0 = (wn << 5) + (lane & 15);
  int kg = lane >> 4;
  float bias0 = prm[320 + n0], bias1 = prm[320 + n0 + 16];
  int wl0 = w << 4;

  // hoist B fragments (constant across j)
  short8 bfr[2][2];
  #pragma unroll
  for (int ks = 0; ks < 2; ks++){
    int kb = kg + (ks << 2);
    bfr[ks][0] = *(const short8*)(Bs + (n0 << 7)        + ((kb ^ (n0 & 7)) << 4));
    bfr[ks][1] = *(const short8*)(Bs + ((n0 + 16) << 7) + ((kb ^ (n0 & 7)) << 4));
  }
  __syncthreads();   // xas transpose complete

  float h[3][16];
  int J0 = jh ? 12 : 0;
  int NJ = jh ? 13 : 12;
  #pragma unroll
  for (int i = 0; i < 16; i++) h[2][i] = 0.f;
  HCOMP(0, J0);
  if (J0 > 0) HCOMP(2, J0 - 1);

  float ss0 = 0.f, ss1 = 0.f, qq0 = 0.f, qq1 = 0.f;

  #pragma unroll
  for (int jj = 0; jj < 13; jj++){
    if (jj >= NJ) break;
    int j = J0 + jj;
    if (j + 1 <= 24){
      switch ((jj + 1) % 3){
        case 0: HCOMP(0, j + 1); break;
        case 1: HCOMP(1, j + 1); break;
        case 2: HCOMP(2, j + 1); break;
      }
    }
    float dj  = (j == 0 || j == 24) ? 2.f : 3.f;
    float rdj = rsqrtf(dj);
    float wgs = 1.f / dj;
    float wgm = (j > 0)  ? rdj * rsqrtf((j == 1)  ? 2.f : 3.f) : 0.f;
    float wgp = (j < 24) ? rdj * rsqrtf((j == 23) ? 2.f : 3.f) : 0.f;
    switch (jj % 3){
      case 0: AGGW(2, 0, 1); break;
      case 1: AGGW(0, 1, 2); break;
      case 2: AGGW(1, 2, 0); break;
    }
    __syncthreads();   // As visible
    f32x4 acc[2][2] = {};
    #pragma unroll
    for (int ks = 0; ks < 2; ks++){
      int kb = kg + (ks << 2);
      short8 a0 = *(const short8*)(As + (m0 << 7)        + ((kb ^ (m0 & 7)) << 4));
      short8 a1 = *(const short8*)(As + ((m0 + 16) << 7) + ((kb ^ (m0 & 7)) << 4));
      acc[0][0] = __builtin_amdgcn_mfma_f32_16x16x32_bf16(a0, bfr[ks][0], acc[0][0], 0, 0, 0);
      acc[0][1] = __builtin_amdgcn_mfma_f32_16x16x32_bf16(a0, bfr[ks][1], acc[0][1], 0, 0, 0);
      acc[1][0] = __builtin_amdgcn_mfma_f32_16x16x32_bf16(a1, bfr[ks][0], acc[1][0], 0, 0, 0);
      acc[1][1] = __builtin_amdgcn_mfma_f32_16x16x32_bf16(a1, bfr[ks][1], acc[1][1], 0, 0, 0);
    }
    __syncthreads();   // As reads done -> reusable next j
    int rowb = (wm << 5) + ((lane >> 4) << 2);
    #pragma unroll
    for (int mi = 0; mi < 2; mi++){
      #pragma unroll
      for (int ni = 0; ni < 2; ni++){
        float bias = ni ? bias1 : bias0;
        int f = n0 + (ni << 4);
        #pragma unroll
        for (int r = 0; r < 4; r++){
          float v = acc[mi][ni][r] + bias;
          if (ni){ ss1 += v; qq1 += v * v; } else { ss0 += v; qq0 += v * v; }
          int rl = rowb + (mi << 4) + r;
          y2t[(size_t)(b * 258 + l0 + rl + 1) * 1600 + j * 64 + f] = f2bf(v);
        }
      }
    }
  }
  ss0 += __shfl_xor(ss0, 16, 64); ss0 += __shfl_xor(ss0, 32, 64);
  ss1 += __shfl_xor(ss1, 16, 64); ss1 += __shfl_xor(ss1, 32, 64);
  qq0 += __shfl_xor(qq0, 16, 64); qq0 += __shfl_xor(qq0, 32, 64);
  qq1 += __shfl_xor(qq1, 16, 64); qq1 += __shfl_xor(qq1, 32, 64);
  if ((lane >> 4) == 0){
    atomicAdd(sum2 + n0, ss0);      atomicAdd(sq2 + n0, qq0);
    atomicAdd(sum2 + n0 + 16, ss1); atomicAdd(sq2 + n0 + 16, qq1);
  }
}

// ---- BN2+lrelu in place on y2t (pads stay zero) + fused BN2-param computation ----
__global__ __launch_bounds__(256) void k_bnapp2(unsigned short* __restrict__ y2t,
                                                const float* __restrict__ sum2,
                                                const float* __restrict__ sq2,
                                                const float* __restrict__ g2,
                                                const float* __restrict__ be2){
  __shared__ float scL[64], shL[64];
  int tid = threadIdx.x;
  if (tid < 64){
    float inv = 1.f / (float)NN_;
    float mean = sum2[tid] * inv;
    float var  = sq2[tid] * inv - mean * mean;
    float s = g2[tid] * rsqrtf(var + EPSV);
    scL[tid] = s; shL[tid] = be2[tid] - s * mean;
  }
  __syncthreads();
  for (unsigned idx = blockIdx.x * 256 + tid; idx < 3276800u; idx += 524288u){
    unsigned b = idx / 51200u;
    unsigned rem = idx - b * 51200u;
    unsigned l = rem / 200u;
    unsigned cg = rem - l * 200u;
    uint4* p = (uint4*)y2t + ((size_t)b * 258 + l + 1) * 200 + cg;
    unsigned f0 = (cg << 3) & 63u;
    float scs[8], shs[8];
    #pragma unroll
    for (int i = 0; i < 8; i++){ scs[i] = scL[f0 + i]; shs[i] = shL[f0 + i]; }
    uint4 v = *p;
    unsigned vv[4] = {v.x,v.y,v.z,v.w};
    unsigned r[4];
    #pragma unroll
    for (int i = 0; i < 4; i++){
      float lo = bf2f(vv[i] & 0xffffu);
      float hi = bf2f(vv[i] >> 16);
      lo = lrelu(fmaf(scs[2*i],   lo, shs[2*i]));
      hi = lrelu(fmaf(scs[2*i+1], hi, shs[2*i+1]));
      r[i] = (unsigned)f2bf(lo) | (((unsigned)f2bf(hi)) << 16);
    }
    *p = make_uint4(r[0],r[1],r[2],r[3]);
  }
}

// ---- conv1 as MFMA GEMM + fused stats3; t-order (cc outer, k inner) for L2 tap reuse ----
#define NT_ 75
__global__ __launch_bounds__(256) void k_conv1(const unsigned short* __restrict__ y2t,
                                               const unsigned short* __restrict__ wt1,
                                               const float* __restrict__ cb1,
                                               float* __restrict__ y3,
                                               float* __restrict__ sum3,
                                               float* __restrict__ sq3){
  __shared__ char smem[32768];
  int bid = blockIdx.x;          // 512
  int blk = ((bid & 7) << 6) | (bid >> 3);
  int b  = blk >> 3;
  int lq = (blk >> 1) & 3;
  int og = blk & 1;
  int l0 = lq << 6;
  int tid = threadIdx.x;
  int w = tid >> 6, lane = tid & 63;
  int wm = w >> 1, wn = w & 1;
  const unsigned short* y2b = y2t + (size_t)b * 412800;
  const unsigned short* wtb = wt1 + (size_t)og * 64 * 1600;

  int rs = (w << 4) + (lane >> 3);
  int cblk = lane & 7;
  int m0 = (wm << 5) + (lane & 15);
  int n0 = (wn << 5) + (lane & 15);
  int kg = lane >> 4;

  f32x4 acc[2][2] = {};

  auto stage = [&](int t, int buf){
    int cc6 = (t * 0x5556) >> 16;          // t / 3 for t < 75
    int k   = t - cc6 * 3;
    int cc  = cc6 << 6;
    const unsigned short* wk = wtb + (size_t)k * 204800;
    #pragma unroll
    for (int i = 0; i < 2; i++){
      int r = rs + (i << 3);
      int sw = (cblk ^ (r & 7)) << 3;
      gl16(y2b + (size_t)(l0 + r + k) * 1600 + cc + sw,
           smem + buf * 16384 + (w << 11) + (i << 10));
      gl16(wk + (size_t)r * 1600 + cc + sw,
           smem + buf * 16384 + 8192 + (w << 11) + (i << 10));
    }
  };

  stage(0, 0);
  __syncthreads();
  #pragma unroll 2
  for (int t = 0; t < NT_; ++t){
    int buf = t & 1;
    if (t + 1 < NT_) stage(t + 1, buf ^ 1);
    const char* Ab = smem + buf * 16384;
    const char* Bb = Ab + 8192;
    #pragma unroll
    for (int ks = 0; ks < 2; ks++){
      int kb = kg + (ks << 2);
      short8 a0 = *(const short8*)(Ab + (m0 << 7)        + ((kb ^ (m0 & 7)) << 4));
      short8 a1 = *(const short8*)(Ab + ((m0 + 16) << 7) + ((kb ^ (m0 & 7)) << 4));
      short8 b0 = *(const short8*)(Bb + (n0 << 7)        + ((kb ^ (n0 & 7)) << 4));
      short8 b1 = *(const short8*)(Bb + ((n0 + 16) << 7) + ((kb ^ (n0 & 7)) << 4));
      acc[0][0] = __builtin_amdgcn_mfma_f32_16x16x32_bf16(a0, b0, acc[0][0], 0, 0, 0);
      acc[0][1] = __builtin_amdgcn_mfma_f32_16x16x32_bf16(a0, b1, acc[0][1], 0, 0, 0);
      acc[1][0] = __builtin_amdgcn_mfma_f32_16x16x32_bf16(a1, b0, acc[1][0], 0, 0, 0);
      acc[1][1] = __builtin_amdgcn_mfma_f32_16x16x32_bf16(a1, b1, acc[1][1], 0, 0, 0);
    }
    __syncthreads();
  }

  int colb = (og << 6) + n0;
  int rowb = l0 + (wm << 5) + ((lane >> 4) << 2);
  float ss0 = 0.f, ss1 = 0.f, qq0 = 0.f, qq1 = 0.f;
  #pragma unroll
  for (int mi = 0; mi < 2; mi++){
    #pragma unroll
    for (int ni = 0; ni < 2; ni++){
      int col = colb + (ni << 4);
      float bias = cb1[col];
      #pragma unroll
      for (int r = 0; r < 4; r++){
        float v = acc[mi][ni][r] + bias;
        if (ni){ ss1 += v; qq1 += v * v; } else { ss0 += v; qq0 += v * v; }
        y3[(size_t)((b << 8) + rowb + (mi << 4) + r) * 128 + col] = v;
      }
    }
  }
  ss0 += __shfl_xor(ss0, 16, 64); ss0 += __shfl_xor(ss0, 32, 64);
  ss1 += __shfl_xor(ss1, 16, 64); ss1 += __shfl_xor(ss1, 32, 64);
  qq0 += __shfl_xor(qq0, 16, 64); qq0 += __shfl_xor(qq0, 32, 64);
  qq1 += __shfl_xor(qq1, 16, 64); qq1 += __shfl_xor(qq1, 32, 64);
  if ((lane >> 4) == 0){
    atomicAdd(sum3 + colb, ss0);      atomicAdd(sq3 + colb, qq0);
    atomicAdd(sum3 + colb + 16, ss1); atomicAdd(sq3 + colb + 16, qq1);
  }
}

// ---- conv2 MFMA + fused BN3-param compute + BN3/lrelu on A-staging + fused stats4 ----
__global__ __launch_bounds__(256) void k_conv2(const float* __restrict__ y3,
                                               const float* __restrict__ sum3,
                                               const float* __restrict__ sq3,
                                               const float* __restrict__ cg1,
                                               const float* __restrict__ cbe1,
                                               const unsigned short* __restrict__ wt2,
                                               const float* __restrict__ cb2,
                                               float* __restrict__ y4,
                                               float* __restrict__ sum4,
                                               float* __restrict__ sq4){
  __shared__ char smem[32768];
  __shared__ float sc3s[128], sh3s[128];
  int blk = blockIdx.x;          // 256 = 64b * 4lq
  int b = blk >> 2, lq = blk & 3;
  int l0 = lq << 6;
  int tid = threadIdx.x;
  int w = tid >> 6, lane = tid & 63;
  int wm = w >> 1, wn = w & 1;
  #pragma unroll
  for (int i = 0; i < 4; i++){
    int r = (w << 4) + (i << 2) + (lane >> 4);
    int sw = (((lane & 15) ^ (r & 7)) << 3);
    gl16(wt2 + (size_t)r * 128 + sw, smem + 16384 + (w << 12) + (i << 10));
  }
  if (tid < 128){
    float inv = 1.f / (float)MM_;
    float mean = sum3[tid] * inv;
    float var  = sq3[tid] * inv - mean * mean;
    float s = cg1[tid] * rsqrtf(var + EPSV);
    sc3s[tid] = s; sh3s[tid] = cbe1[tid] - s * mean;
  }
  __syncthreads();
  #pragma unroll
  for (int i = 0; i < 4; i++){
    int idx = tid + (i << 8);
    int r = idx >> 4, s = idx & 15;
    const float* src = y3 + (size_t)((b << 8) + l0 + r) * 128 + (s << 3);
    float4 v0 = *(const float4*)(src);
    float4 v1 = *(const float4*)(src + 4);
    float4 c0 = *(const float4*)(sc3s + (s << 3));
    float4 c1 = *(const float4*)(sc3s + (s << 3) + 4);
    float4 h0 = *(const float4*)(sh3s + (s << 3));
    float4 h1 = *(const float4*)(sh3s + (s << 3) + 4);
    uint4 u;
    u.x = (unsigned)f2bf(lrelu(fmaf(c0.x, v0.x, h0.x))) |
          ((unsigned)f2bf(lrelu(fmaf(c0.y, v0.y, h0.y))) << 16);
    u.y = (unsigned)f2bf(lrelu(fmaf(c0.z, v0.z, h0.z))) |
          ((unsigned)f2bf(lrelu(fmaf(c0.w, v0.w, h0.w))) << 16);
    u.z = (unsigned)f2bf(lrelu(fmaf(c1.x, v1.x, h1.x))) |
          ((unsigned)f2bf(lrelu(fmaf(c1.y, v1.y, h1.y))) << 16);
    u.w = (unsigned)f2bf(lrelu(fmaf(c1.z, v1.z, h1.z))) |
          ((unsigned)f2bf(lrelu(fmaf(c1.w, v1.w, h1.w))) << 16);
    *(uint4*)(smem + r * 256 + ((s ^ (r & 7)) << 4)) = u;
  }
  __syncthreads();
  f32x4 acc[2][2] = {};
  int m0 = (wm << 5) + (lane & 15);
  int n0 = (wn << 5) + (lane & 15);
  int kg = lane >> 4;
  const char* Ab = smem;
  const char* Bb = smem + 16384;
  #pragma unroll
  for (int ks = 0; ks < 4; ks++){
    int kb = kg + (ks << 2);
    short8 a0 = *(const short8*)(Ab + (m0 << 8)        + ((kb ^ (m0 & 7)) << 4));
    short8 a1 = *(const short8*)(Ab + ((m0 + 16) << 8) + ((kb ^ (m0 & 7)) << 4));
    short8 b0 = *(const short8*)(Bb + (n0 << 8)        + ((kb ^ (n0 & 7)) << 4));
    short8 b1 = *(const short8*)(Bb + ((n0 + 16) << 8) + ((kb ^ (n0 & 7)) << 4));
    acc[0][0] = __builtin_amdgcn_mfma_f32_16x16x32_bf16(a0, b0, acc[0][0], 0, 0, 0);
    acc[0][1] = __builtin_amdgcn_mfma_f32_16x16x32_bf16(a0, b1, acc[0][1], 0, 0, 0);
    acc[1][0] = __builtin_amdgcn_mfma_f32_16x16x32_bf16(a1, b0, acc[1][0], 0, 0, 0);
    acc[1][1] = __builtin_amdgcn_mfma_f32_16x16x32_bf16(a1, b1, acc[1][1], 0, 0, 0);
  }
  int rowb = l0 + (wm << 5) + ((lane >> 4) << 2);
  float ss0 = 0.f, ss1 = 0.f, qq0 = 0.f, qq1 = 0.f;
  #pragma unroll
  for (int mi = 0; mi < 2; mi++){
    #pragma unroll
    for (int ni = 0; ni < 2; ni++){
      int f = n0 + (ni << 4);
      float bias = cb2[f];
      #pragma unroll
      for (int r = 0; r < 4; r++){
        float v = acc[mi][ni][r] + bias;
        if (ni){ ss1 += v; qq1 += v * v; } else { ss0 += v; qq0 += v * v; }
        y4[(size_t)((b << 8) + rowb + (mi << 4) + r) * 64 + f] = v;
      }
    }
  }
  ss0 += __shfl_xor(ss0, 16, 64); ss0 += __shfl_xor(ss0, 32, 64);
  ss1 += __shfl_xor(ss1, 16, 64); ss1 += __shfl_xor(ss1, 32, 64);
  qq0 += __shfl_xor(qq0, 16, 64); qq0 += __shfl_xor(qq0, 32, 64);
  qq1 += __shfl_xor(qq1, 16, 64); qq1 += __shfl_xor(qq1, 32, 64);
  if ((lane >> 4) == 0){
    atomicAdd(sum4 + n0, ss0);      atomicAdd(sq4 + n0, qq0);
    atomicAdd(sum4 + n0 + 16, ss1); atomicAdd(sq4 + n0 + 16, qq1);
  }
}

// ---- final: out = lrelu(bn4(y4)) + fused BN4-param compute ----
__global__ __launch_bounds__(256) void k_final(const float* __restrict__ y4,
                                               const float* __restrict__ sum4,
                                               const float* __restrict__ sq4,
                                               const float* __restrict__ cg2,
                                               const float* __restrict__ cbe2,
                                               float* __restrict__ out){
  __shared__ float sc4s[64], sh4s[64];
  int tid = threadIdx.x;
  if (tid < 64){
    float inv = 1.f / (float)MM_;
    float mean = sum4[tid] * inv;
    float var  = sq4[tid] * inv - mean * mean;
    float s = cg2[tid] * rsqrtf(var + EPSV);
    sc4s[tid] = s; sh4s[tid] = cbe2[tid] - s * mean;
  }
  __syncthreads();
  unsigned q = blockIdx.x * 256 + tid;
  unsigned f0 = (q & 15) << 2;
  float4 v = ((const float4*)y4)[q];
  float4 sc = *(const float4*)(sc4s + f0);
  float4 sh = *(const float4*)(sh4s + f0);
  v.x = lrelu(fmaf(sc.x, v.x, sh.x));
  v.y = lrelu(fmaf(sc.y, v.y, sh.y));
  v.z = lrelu(fmaf(sc.z, v.z, sh.z));
  v.w = lrelu(fmaf(sc.w, v.w, sh.w));
  ((float4*)out)[q] = v;
}

extern "C" void kernel_launch(void* const* d_in, const int* in_sizes, int n_in,
                              void* d_out, int out_size, void* d_ws, size_t ws_size,
                              hipStream_t stream){
  const float* x    = (const float*)d_in[0];
  const float* W1   = (const float*)d_in[4];
  const float* b1   = (const float*)d_in[5];
  const float* g1   = (const float*)d_in[6];
  const float* be1  = (const float*)d_in[7];
  const float* W2   = (const float*)d_in[8];
  const float* b2   = (const float*)d_in[9];
  const float* g2   = (const float*)d_in[10];
  const float* be2  = (const float*)d_in[11];
  const float* cw1  = (const float*)d_in[12];
  const float* cb1  = (const float*)d_in[13];
  const float* cg1  = (const float*)d_in[14];
  const float* cbe1 = (const float*)d_in[15];
  const float* cw2  = (const float*)d_in[16];
  const float* cb2  = (const float*)d_in[17];
  const float* cg2  = (const float*)d_in[18];
  const float* cbe2 = (const float*)d_in[19];

  char* ws = (char*)d_ws;
  unsigned short* y2t  = (unsigned short*)(ws + WS_Y2T);
  float* xa            = (float*)(ws + WS_XA);
  unsigned short* wt1  = (unsigned short*)(ws + WS_WT1);
  unsigned short* wt2  = (unsigned short*)(ws + WS_WT2);
  unsigned short* wt2g = (unsigned short*)(ws + WS_WT2G);
  float* y3            = (float*)(ws + WS_Y3);
  float* y4            = (float*)(ws + WS_Y4);
  float* st            = (float*)(ws + WS_ST);

  if (ws_size < WS_ST + ST_COUNT * 4) return;

  hipMemsetAsync(st, 0, ST_COUNT * 4, stream);
  k_pre   <<<2096, 256, 0, stream>>>(cw1, W2, cw2, x, wt1, wt2, wt2g, y2t,
                                     xa, st + ST_S9);
  k_gcn2m <<<512, 256, 0, stream>>>(xa, W1, st + ST_S9, b1, g1, be1, b2, wt2g,
                                    y2t, st + ST_SUM2, st + ST_SQ2);
  k_bnapp2<<<2048, 256, 0, stream>>>(y2t, st + ST_SUM2, st + ST_SQ2, g2, be2);
  k_conv1 <<<512, 256, 0, stream>>>(y2t, wt1, cb1, y3, st + ST_SUM3, st + ST_SQ3);
  k_conv2 <<<256, 256, 0, stream>>>(y3, st + ST_SUM3, st + ST_SQ3, cg1, cbe1,
                                    wt2, cb2, y4, st + ST_SUM4, st + ST_SQ4);
  k_final <<<1024, 256, 0, stream>>>(y4, st + ST_SUM4, st + ST_SQ4, cg2, cbe2,
                                     (float*)d_out);
}